// Round 13
// baseline (51.734 us; speedup 1.0000x reference)
//
#include <hip/hip_runtime.h>

// SpatialCoherenceLoss — R13: SINGLE fused dispatch. No prep kernel, no ws
// round-trip (pbf/params deleted), no global_load_lds. Blocks read fp32 pred
// directly (read-only -> clean L2/IC lines), convert to bf16 in regs, ds_write
// swizzled LDS tiles, sq computed on rounded values inline. R10's dynamic
// queue (512 blocks / 528 items, diag last). ctr zeroed via hipMemsetAsync.
// Tests the last kernel-side floor candidates vs the harness's per-replay
// 256MiB poison-fill (~39us at 85% HBM) as the external floor.
// loss = mean_{i,j} exp(-100*||s_i-s_j||^2) * (sq_i + sq_j - 2<p_i,p_j>)

#define NPTS 8192
#define DIM  64
#define TILE 128
#define NT   (NPTS / TILE)              // 64 tiles
#define NSG  (NT / 2)                   // 32 super rows
#define NOFF (NSG * (NSG - 1) / 2)      // 496 off-diag items
#define NITEMS (NOFF + NSG)             // 528 items
#define NBLK 512

typedef __attribute__((ext_vector_type(8))) short bf16x8;
typedef __attribute__((ext_vector_type(4))) float f32x4;
typedef __attribute__((ext_vector_type(4))) float fv4;

constexpr float kCoordScale = 12.0112244f;  // sqrt(100*log2(e))

__device__ __forceinline__ ushort f2bf(float x) {  // RNE fp32->bf16
    unsigned u = __builtin_bit_cast(unsigned, x);
    unsigned r = (u + 0x7fffu + ((u >> 16) & 1u)) >> 16;
    return (ushort)r;
}
__device__ __forceinline__ float bf2f(ushort b) {
    unsigned u = ((unsigned)b) << 16;
    return __builtin_bit_cast(float, u);
}
// pack 8 fp32 -> bf16x8 (RNE), accumulate sum of squares of ROUNDED values
__device__ __forceinline__ bf16x8 pack8(fv4 a, fv4 b, float& sqp) {
    bf16x8 c;
    ushort u;
    float f;
    u = f2bf(a.x); f = bf2f(u); sqp = fmaf(f, f, sqp); c[0] = (short)u;
    u = f2bf(a.y); f = bf2f(u); sqp = fmaf(f, f, sqp); c[1] = (short)u;
    u = f2bf(a.z); f = bf2f(u); sqp = fmaf(f, f, sqp); c[2] = (short)u;
    u = f2bf(a.w); f = bf2f(u); sqp = fmaf(f, f, sqp); c[3] = (short)u;
    u = f2bf(b.x); f = bf2f(u); sqp = fmaf(f, f, sqp); c[4] = (short)u;
    u = f2bf(b.y); f = bf2f(u); sqp = fmaf(f, f, sqp); c[5] = (short)u;
    u = f2bf(b.z); f = bf2f(u); sqp = fmaf(f, f, sqp); c[6] = (short)u;
    u = f2bf(b.w); f = bf2f(u); sqp = fmaf(f, f, sqp); c[7] = (short)u;
    return c;
}

// LDS: 4 tile slots x 16KB @0, 4 param slots x 2KB @65536 -> 72.5KB, 2 blk/CU.
__launch_bounds__(256, 2)
__global__ void scl_fused_kernel(const float* __restrict__ pred,
                                 const float* __restrict__ spat,
                                 float* __restrict__ partial,
                                 unsigned* __restrict__ ctr,
                                 float* __restrict__ out) {
    __shared__ __align__(16) char smem[73728];
    __shared__ float red[4];
    __shared__ int curit;
    __shared__ int lastflag;

    const int tid  = threadIdx.x;
    const int lane = tid & 63;
    const int wave = tid >> 6;
    const int fr = lane & 15;
    const int h  = lane >> 4;

    unsigned* qctr = ctr;
    unsigned* done = ctr + 1;

    for (;;) {
        __syncthreads();                       // prev iter's LDS readers done
        if (tid == 0) curit = (int)atomicAdd(qctr, 1u);
        __syncthreads();
        const int it = curit;
        if (it >= NITEMS) break;

        // decode: [0,496) off-diag si<sj; [496,528) diag
        int si, sj;
        bool diag;
        if (it >= NOFF) {
            si = sj = it - NOFF; diag = true;
        } else {
            int k = it, b = 0; si = 0;
            while (b + (NSG - 1 - si) <= k) { b += NSG - 1 - si; ++si; }
            sj = si + 1 + (k - b); diag = false;
        }
        const int tiles[4] = {2 * si, 2 * si + 1, 2 * sj, 2 * sj + 1};

        // ---- reg-stage: fp32 -> bf16 swizzled LDS + params ----
        {
            const int r = tid >> 1;            // row within tile
            const int half = tid & 1;          // which 32-float half
            #pragma unroll 1
            for (int s = 0; s < 4; ++s) {
                const int g = tiles[s] * TILE + r;
                const fv4* srcp = (const fv4*)(pred + (size_t)g * DIM + half * 32);
                char* dst = smem + (unsigned)s * 16384u + (unsigned)r * 128u;
                const unsigned sw = ((unsigned)r & 7u) << 4;
                float sqp = 0.f;
                #pragma unroll
                for (int k = 0; k < 4; ++k) {
                    bf16x8 c = pack8(srcp[2 * k], srcp[2 * k + 1], sqp);
                    unsigned cb = (unsigned)(half * 64 + k * 16);
                    *(bf16x8*)(dst + (cb ^ sw)) = c;
                }
                sqp += __shfl_xor(sqp, 1, 64);
                if (half == 0) {
                    float4 pm;
                    pm.x = sqp;
                    pm.y = spat[2 * g] * kCoordScale;
                    pm.z = spat[2 * g + 1] * kCoordScale;
                    pm.w = 0.f;
                    *(float4*)(smem + 65536u + (unsigned)s * 2048u +
                               (unsigned)r * 16u) = pm;
                }
            }
        }
        __syncthreads();                       // tiles + params visible

        // ---- compute (R12 compact): items (0,2)(0,3)(1,2)(1,3) ----
        float loss = 0.f;
        #pragma unroll 1
        for (int m = 0; m < 4; ++m) {
            if (m == 2 && diag) continue;      // transpose of m=1
            const int sa = m >> 1, sb = 2 + (m & 1);

            const char* aB = smem + (unsigned)sa * 16384u;
            const char* bB = smem + (unsigned)sb * 16384u;
            const float4* pA = (const float4*)(smem + 65536u + (unsigned)sa * 2048u);
            const float4* pB = (const float4*)(smem + 65536u + (unsigned)sb * 2048u);

            const unsigned row0 = (unsigned)(wave * 32 + fr);
            const unsigned row1 = row0 + 16u;
            const unsigned sw0 = (row0 & 7u) << 4, sw1 = (row1 & 7u) << 4;
            bf16x8 af00 = *(const bf16x8*)(aB + row0 * 128u + (((unsigned)(h * 16)) ^ sw0));
            bf16x8 af01 = *(const bf16x8*)(aB + row0 * 128u + (((unsigned)(64 + h * 16)) ^ sw0));
            bf16x8 af10 = *(const bf16x8*)(aB + row1 * 128u + (((unsigned)(h * 16)) ^ sw1));
            bf16x8 af11 = *(const bf16x8*)(aB + row1 * 128u + (((unsigned)(64 + h * 16)) ^ sw1));

            float rsq0[4], rsx0[4], rsy0[4], rsq1[4], rsx1[4], rsy1[4];
            #pragma unroll
            for (int reg = 0; reg < 4; ++reg) {
                float4 rp = pA[wave * 32 + h * 4 + reg];
                rsq0[reg] = rp.x; rsx0[reg] = rp.y; rsy0[reg] = rp.z;
                float4 rq = pA[wave * 32 + 16 + h * 4 + reg];
                rsq1[reg] = rq.x; rsx1[reg] = rq.y; rsy1[reg] = rq.z;
            }

            float tl = 0.f;
            #pragma unroll 1
            for (int cb = 0; cb < 8; ++cb) {
                unsigned rowB = (unsigned)(cb * 16 + fr);
                unsigned sw = (rowB & 7u) << 4;
                const char* bb = bB + rowB * 128u;
                bf16x8 b0 = *(const bf16x8*)(bb + (((unsigned)(h * 16)) ^ sw));
                bf16x8 b1 = *(const bf16x8*)(bb + (((unsigned)(64 + h * 16)) ^ sw));
                f32x4 a0 = (f32x4){0.f, 0.f, 0.f, 0.f};
                f32x4 a1 = (f32x4){0.f, 0.f, 0.f, 0.f};
                a0 = __builtin_amdgcn_mfma_f32_16x16x32_bf16(af00, b0, a0, 0, 0, 0);
                a0 = __builtin_amdgcn_mfma_f32_16x16x32_bf16(af01, b1, a0, 0, 0, 0);
                a1 = __builtin_amdgcn_mfma_f32_16x16x32_bf16(af10, b0, a1, 0, 0, 0);
                a1 = __builtin_amdgcn_mfma_f32_16x16x32_bf16(af11, b1, a1, 0, 0, 0);

                float4 cp = pB[cb * 16 + fr];
                #pragma unroll
                for (int reg = 0; reg < 4; ++reg) {
                    {
                        float dx = rsx0[reg] - cp.y;
                        float dy = rsy0[reg] - cp.z;
                        float nd2 = fmaf(-dx, dx, (-dy) * dy);
                        float w = __builtin_amdgcn_exp2f(nd2);
                        float pd = fmaf(-2.f, a0[reg], rsq0[reg] + cp.x);
                        tl = fmaf(w, pd, tl);
                    }
                    {
                        float dx = rsx1[reg] - cp.y;
                        float dy = rsy1[reg] - cp.z;
                        float nd2 = fmaf(-dx, dx, (-dy) * dy);
                        float w = __builtin_amdgcn_exp2f(nd2);
                        float pd = fmaf(-2.f, a1[reg], rsq1[reg] + cp.x);
                        tl = fmaf(w, pd, tl);
                    }
                }
            }
            loss += (diag && (m == 0 || m == 3)) ? tl : 2.f * tl;
        }

        #pragma unroll
        for (int off = 32; off > 0; off >>= 1)
            loss += __shfl_down(loss, off, 64);
        if (lane == 0) red[wave] = loss;
        __syncthreads();
        if (tid == 0) {
            partial[it] = (red[0] + red[1]) + (red[2] + red[3]);
            __threadfence();
            unsigned old = atomicAdd(done, 1u);
            lastflag = (old == (unsigned)(NITEMS - 1)) ? 1 : 0;
            if (lastflag) __threadfence();
        }
        __syncthreads();
        if (lastflag) {                        // all partials visible
            float s = 0.f;
            for (int idx = tid; idx < NITEMS; idx += 256) s += partial[idx];
            #pragma unroll
            for (int off = 32; off > 0; off >>= 1)
                s += __shfl_down(s, off, 64);
            if (lane == 0) red[wave] = s;
            __syncthreads();
            if (tid == 0)
                out[0] = ((red[0] + red[1]) + (red[2] + red[3])) *
                         (1.0f / (8192.0f * 8192.0f));
            __syncthreads();
        }
    }
}

extern "C" void kernel_launch(void* const* d_in, const int* in_sizes, int n_in,
                              void* d_out, int out_size, void* d_ws, size_t ws_size,
                              hipStream_t stream) {
    const float* pred = (const float*)d_in[0];
    const float* spat = (const float*)d_in[1];
    float* out = (float*)d_out;

    float*    partial = (float*)d_ws;                           // 528 floats
    unsigned* ctr     = (unsigned*)(partial + ((NITEMS + 3) & ~3));

    hipMemsetAsync(ctr, 0, 2 * sizeof(unsigned), stream);       // queue + done
    scl_fused_kernel<<<NBLK, 256, 0, stream>>>(pred, spat, partial, ctr, out);
}

// Round 14
// 36.500 us; speedup vs baseline: 1.4174x; 1.4174x over previous
//
#include <hip/hip_runtime.h>

// SpatialCoherenceLoss — R14: R8 base (best measured: prep + global_load_lds,
// 528 super-blocks, 4-slot LDS, vmcnt(8)/vmcnt(0) schedule) + ONE change:
// epilogue uses 8 independent accumulators tacc[rb][reg] instead of a single
// tl (64-deep fmaf chain -> 8-deep; targets R9's measured 10.7us/pass at
// VALUBusy 41% = dependency-stall-bound).
// loss = mean_{i,j} exp(-100*||s_i-s_j||^2) * (sq_i + sq_j - 2<p_i,p_j>)

#define NPTS 8192
#define DIM  64
#define TILE 128
#define NT   (NPTS / TILE)              // 64 tiles
#define NSG  (NT / 2)                   // 32 super rows
#define NSUP (NSG * (NSG + 1) / 2)      // 528 blocks

typedef __attribute__((ext_vector_type(8))) short bf16x8;
typedef __attribute__((ext_vector_type(4))) float f32x4;
typedef __attribute__((ext_vector_type(4))) float fv4;
typedef __attribute__((ext_vector_type(4))) ushort usv4;

#define AS3(p) ((__attribute__((address_space(3))) void*)(p))
#define AS1(p) ((const __attribute__((address_space(1))) void*)(p))

__device__ __forceinline__ ushort f2bf(float x) {
    unsigned u = __builtin_bit_cast(unsigned, x);
    unsigned r = (u + 0x7fffu + ((u >> 16) & 1u)) >> 16;
    return (ushort)r;
}
__device__ __forceinline__ float bf2f(ushort b) {
    unsigned u = ((unsigned)b) << 16;
    return __builtin_bit_cast(float, u);
}

constexpr float kCoordScale = 12.0112244f;  // sqrt(100*log2(e))

__global__ void scl_prep_kernel(const float* __restrict__ pred,
                                const float* __restrict__ spat,
                                ushort* __restrict__ pbf,
                                float4* __restrict__ params,
                                unsigned* __restrict__ ctr) {
    int i = blockIdx.x * blockDim.x + threadIdx.x;
    if (i == 0) ctr[0] = 0u;
    const fv4* pr = (const fv4*)(pred + (size_t)i * DIM);
    usv4* po = (usv4*)(pbf + (size_t)i * DIM);
    float sq = 0.f;
    #pragma unroll
    for (int k = 0; k < DIM / 4; ++k) {
        fv4 v = __builtin_nontemporal_load(&pr[k]);
        usv4 o;
        o.x = f2bf(v.x); o.y = f2bf(v.y); o.z = f2bf(v.z); o.w = f2bf(v.w);
        float a = bf2f(o.x), b = bf2f(o.y), c = bf2f(o.z), d = bf2f(o.w);
        sq += a * a + b * b + c * c + d * d;
        __builtin_nontemporal_store(o, &po[k]);
    }
    fv4 pm;
    pm.x = sq;
    pm.y = spat[2 * i] * kCoordScale;
    pm.z = spat[2 * i + 1] * kCoordScale;
    pm.w = 0.f;
    __builtin_nontemporal_store(pm, (fv4*)&params[i]);
}

// LDS: 4 tile slots x 16KB @0, 4 param slots x 2KB @65536 -> 72.5KB, 2 blk/CU.
__launch_bounds__(256, 2)
__global__ void scl_mfma_kernel(const ushort* __restrict__ pbf,
                                const float4* __restrict__ params,
                                float* __restrict__ partial,
                                unsigned* __restrict__ ctr,
                                float* __restrict__ out) {
    __shared__ __align__(16) char smem[73728];
    __shared__ float red[4];
    __shared__ int lastflag;

    const int tid  = threadIdx.x;
    const int lane = tid & 63;
    const int wave = tid >> 6;
    const int fr = lane & 15;
    const int h  = lane >> 4;

    int t = blockIdx.x;
    int si = 0, base = 0;
    while (base + (NSG - si) <= t) { base += NSG - si; ++si; }
    const int sj = si + (t - base);
    const bool diag = (si == sj);
    const int tiles[4] = {2 * si, 2 * si + 1, 2 * sj, 2 * sj + 1};

    auto stageTile = [&](int slot) {
        const char* g = (const char*)(pbf + (size_t)tiles[slot] * TILE * DIM);
        #pragma unroll
        for (int s4 = 0; s4 < 4; ++s4) {
            unsigned L = (unsigned)tid * 16u + (unsigned)s4 * 4096u;
            unsigned row = L >> 7;
            unsigned src = (L & ~127u) | ((L & 127u) ^ ((row & 7u) << 4));
            unsigned dst = (unsigned)slot * 16384u + (unsigned)wave * 1024u +
                           (unsigned)s4 * 4096u;
            __builtin_amdgcn_global_load_lds(AS1(g + src), AS3(smem + dst), 16, 0, 0);
        }
    };

    stageTile(0);
    stageTile(2);
    {
        const char* gp = (const char*)(params + tiles[wave] * TILE);
        #pragma unroll
        for (int s2 = 0; s2 < 2; ++s2) {
            unsigned so  = (unsigned)s2 * 1024u + (unsigned)lane * 16u;
            unsigned dst = 65536u + (unsigned)wave * 2048u + (unsigned)s2 * 1024u;
            __builtin_amdgcn_global_load_lds(AS1(gp + so), AS3(smem + dst), 16, 0, 0);
        }
    }
    stageTile(1);
    stageTile(3);

    auto computeItem = [&](int sa, int sb) -> float {
        const char* aB = smem + (unsigned)sa * 16384u;
        const char* bB = smem + (unsigned)sb * 16384u;
        const float4* pA = (const float4*)(smem + 65536u + (unsigned)sa * 2048u);
        const float4* pB = (const float4*)(smem + 65536u + (unsigned)sb * 2048u);

        bf16x8 afrag[2][2];
        #pragma unroll
        for (int rb = 0; rb < 2; ++rb)
            #pragma unroll
            for (int ks = 0; ks < 2; ++ks) {
                unsigned row = (unsigned)(wave * 32 + rb * 16 + fr);
                unsigned off = (unsigned)(ks * 64 + h * 16);
                afrag[rb][ks] =
                    *(const bf16x8*)(aB + row * 128u + (off ^ ((row & 7u) << 4)));
            }

        f32x4 acc[2][8];
        #pragma unroll
        for (int rb = 0; rb < 2; ++rb)
            #pragma unroll
            for (int cb = 0; cb < 8; ++cb)
                acc[rb][cb] = (f32x4){0.f, 0.f, 0.f, 0.f};

        #pragma unroll
        for (int cb = 0; cb < 8; ++cb) {
            unsigned rowB = (unsigned)(cb * 16 + fr);
            unsigned sw = (rowB & 7u) << 4;
            const char* bb = bB + rowB * 128u;
            bf16x8 b0 = *(const bf16x8*)(bb + (((unsigned)(h * 16)) ^ sw));
            bf16x8 b1 = *(const bf16x8*)(bb + (((unsigned)(64 + h * 16)) ^ sw));
            #pragma unroll
            for (int rb = 0; rb < 2; ++rb) {
                acc[rb][cb] = __builtin_amdgcn_mfma_f32_16x16x32_bf16(
                    afrag[rb][0], b0, acc[rb][cb], 0, 0, 0);
                acc[rb][cb] = __builtin_amdgcn_mfma_f32_16x16x32_bf16(
                    afrag[rb][1], b1, acc[rb][cb], 0, 0, 0);
            }
        }

        float rsq[2][4], rsx[2][4], rsy[2][4];
        #pragma unroll
        for (int rb = 0; rb < 2; ++rb)
            #pragma unroll
            for (int reg = 0; reg < 4; ++reg) {
                float4 rp = pA[wave * 32 + rb * 16 + h * 4 + reg];
                rsq[rb][reg] = rp.x; rsx[rb][reg] = rp.y; rsy[rb][reg] = rp.z;
            }

        // 8 independent accumulator chains (was 1) — break the 64-deep
        // fmaf latency chain that serialized the epilogue.
        float tacc[2][4];
        #pragma unroll
        for (int rb = 0; rb < 2; ++rb)
            #pragma unroll
            for (int reg = 0; reg < 4; ++reg)
                tacc[rb][reg] = 0.f;

        #pragma unroll
        for (int cb = 0; cb < 8; ++cb) {
            float4 cp = pB[cb * 16 + fr];
            #pragma unroll
            for (int rb = 0; rb < 2; ++rb)
                #pragma unroll
                for (int reg = 0; reg < 4; ++reg) {
                    float dot = acc[rb][cb][reg];
                    float dx = rsx[rb][reg] - cp.y;
                    float dy = rsy[rb][reg] - cp.z;
                    float nd2 = fmaf(-dx, dx, (-dy) * dy);
                    float w = __builtin_amdgcn_exp2f(nd2);
                    float pd = fmaf(-2.f, dot, rsq[rb][reg] + cp.x);
                    tacc[rb][reg] = fmaf(w, pd, tacc[rb][reg]);
                }
        }
        float tl = 0.f;
        #pragma unroll
        for (int rb = 0; rb < 2; ++rb)
            #pragma unroll
            for (int reg = 0; reg < 4; ++reg)
                tl += tacc[rb][reg];
        return tl;
    };

    float loss = 0.f;
    asm volatile("s_waitcnt vmcnt(8)" ::: "memory");  // slots 0,2 + params
    __syncthreads();
    {
        float tl = computeItem(0, 2);
        loss += diag ? tl : 2.f * tl;
    }
    asm volatile("s_waitcnt vmcnt(0)" ::: "memory");
    __syncthreads();
    loss += 2.f * computeItem(0, 3);
    if (!diag) loss += 2.f * computeItem(1, 2);
    {
        float tl = computeItem(1, 3);
        loss += diag ? tl : 2.f * tl;
    }

    #pragma unroll
    for (int off = 32; off > 0; off >>= 1)
        loss += __shfl_down(loss, off, 64);
    if (lane == 0) red[wave] = loss;
    __syncthreads();
    if (tid == 0) {
        partial[blockIdx.x] = (red[0] + red[1]) + (red[2] + red[3]);
        __threadfence();
        unsigned old = atomicAdd(ctr, 1u);
        lastflag = (old == (unsigned)(NSUP - 1)) ? 1 : 0;
        if (lastflag) __threadfence();
    }
    __syncthreads();
    if (lastflag) {
        float s = 0.f;
        for (int idx = tid; idx < NSUP; idx += 256) s += partial[idx];
        #pragma unroll
        for (int off = 32; off > 0; off >>= 1)
            s += __shfl_down(s, off, 64);
        if (lane == 0) red[wave] = s;
        __syncthreads();
        if (tid == 0)
            out[0] = ((red[0] + red[1]) + (red[2] + red[3])) *
                     (1.0f / (8192.0f * 8192.0f));
    }
}

extern "C" void kernel_launch(void* const* d_in, const int* in_sizes, int n_in,
                              void* d_out, int out_size, void* d_ws, size_t ws_size,
                              hipStream_t stream) {
    const float* pred = (const float*)d_in[0];
    const float* spat = (const float*)d_in[1];
    float* out = (float*)d_out;

    ushort*   pbf     = (ushort*)d_ws;                                    // 1 MB
    float4*   params  = (float4*)((char*)d_ws + (size_t)NPTS * DIM * 2);  // 128 KB
    float*    partial = (float*)((char*)params + NPTS * sizeof(float4));  // 2.1 KB
    unsigned* ctr     = (unsigned*)(partial + ((NSUP + 3) & ~3));

    scl_prep_kernel<<<NPTS / 256, 256, 0, stream>>>(pred, spat, pbf, params, ctr);
    scl_mfma_kernel<<<NSUP, 256, 0, stream>>>(pbf, params, partial, ctr, out);
}

// Round 15
// 35.033 us; speedup vs baseline: 1.4767x; 1.0419x over previous
//
#include <hip/hip_runtime.h>

// SpatialCoherenceLoss — R15: R14 base + two pipe-content cuts:
//  (1) sqrt2-trick params {sq, r2*sx', r2*sy', -(sx'^2+sy'^2)}:
//      nd2 = fma(rx,cx, fma(ry,cy, rK+cK)) -> 6 VALU/pair (was 8).
//  (2) A-frags + row params reload only on sa change (2x/block not 4x).
// Marginal pass is multi-pipe issue-limited (LDS 5.9 + VALU 3.5 + trans/MFMA
// overlapped = 10.7 measured); this trims the two biggest pipe terms.
// loss = mean_{i,j} exp(-100*||s_i-s_j||^2) * (sq_i + sq_j - 2<p_i,p_j>)

#define NPTS 8192
#define DIM  64
#define TILE 128
#define NT   (NPTS / TILE)              // 64 tiles
#define NSG  (NT / 2)                   // 32 super rows
#define NSUP (NSG * (NSG + 1) / 2)      // 528 blocks

typedef __attribute__((ext_vector_type(8))) short bf16x8;
typedef __attribute__((ext_vector_type(4))) float f32x4;
typedef __attribute__((ext_vector_type(4))) float fv4;
typedef __attribute__((ext_vector_type(4))) ushort usv4;

#define AS3(p) ((__attribute__((address_space(3))) void*)(p))
#define AS1(p) ((const __attribute__((address_space(1))) void*)(p))

__device__ __forceinline__ ushort f2bf(float x) {
    unsigned u = __builtin_bit_cast(unsigned, x);
    unsigned r = (u + 0x7fffu + ((u >> 16) & 1u)) >> 16;
    return (ushort)r;
}
__device__ __forceinline__ float bf2f(ushort b) {
    unsigned u = ((unsigned)b) << 16;
    return __builtin_bit_cast(float, u);
}

constexpr float kCoordScale = 12.0112244f;   // sqrt(100*log2(e))
constexpr float kRt2Scale   = 16.9864835f;   // sqrt(2)*kCoordScale

__global__ void scl_prep_kernel(const float* __restrict__ pred,
                                const float* __restrict__ spat,
                                ushort* __restrict__ pbf,
                                float4* __restrict__ params,
                                unsigned* __restrict__ ctr) {
    int i = blockIdx.x * blockDim.x + threadIdx.x;
    if (i == 0) ctr[0] = 0u;
    const fv4* pr = (const fv4*)(pred + (size_t)i * DIM);
    usv4* po = (usv4*)(pbf + (size_t)i * DIM);
    float sq = 0.f;
    #pragma unroll
    for (int k = 0; k < DIM / 4; ++k) {
        fv4 v = __builtin_nontemporal_load(&pr[k]);
        usv4 o;
        o.x = f2bf(v.x); o.y = f2bf(v.y); o.z = f2bf(v.z); o.w = f2bf(v.w);
        float a = bf2f(o.x), b = bf2f(o.y), c = bf2f(o.z), d = bf2f(o.w);
        sq += a * a + b * b + c * c + d * d;
        __builtin_nontemporal_store(o, &po[k]);
    }
    float sx = spat[2 * i] * kCoordScale;        // scaled coord
    float sy = spat[2 * i + 1] * kCoordScale;
    fv4 pm;
    pm.x = sq;
    pm.y = spat[2 * i] * kRt2Scale;              // sqrt(2)*sx'
    pm.z = spat[2 * i + 1] * kRt2Scale;          // sqrt(2)*sy'
    pm.w = -fmaf(sx, sx, sy * sy);               // -(sx'^2+sy'^2)
    __builtin_nontemporal_store(pm, (fv4*)&params[i]);
}

// LDS: 4 tile slots x 16KB @0, 4 param slots x 2KB @65536 -> 72.5KB, 2 blk/CU.
__launch_bounds__(256, 2)
__global__ void scl_mfma_kernel(const ushort* __restrict__ pbf,
                                const float4* __restrict__ params,
                                float* __restrict__ partial,
                                unsigned* __restrict__ ctr,
                                float* __restrict__ out) {
    __shared__ __align__(16) char smem[73728];
    __shared__ float red[4];
    __shared__ int lastflag;

    const int tid  = threadIdx.x;
    const int lane = tid & 63;
    const int wave = tid >> 6;
    const int fr = lane & 15;
    const int h  = lane >> 4;

    int t = blockIdx.x;
    int si = 0, base = 0;
    while (base + (NSG - si) <= t) { base += NSG - si; ++si; }
    const int sj = si + (t - base);
    const bool diag = (si == sj);
    const int tiles[4] = {2 * si, 2 * si + 1, 2 * sj, 2 * sj + 1};

    auto stageTile = [&](int slot) {
        const char* g = (const char*)(pbf + (size_t)tiles[slot] * TILE * DIM);
        #pragma unroll
        for (int s4 = 0; s4 < 4; ++s4) {
            unsigned L = (unsigned)tid * 16u + (unsigned)s4 * 4096u;
            unsigned row = L >> 7;
            unsigned src = (L & ~127u) | ((L & 127u) ^ ((row & 7u) << 4));
            unsigned dst = (unsigned)slot * 16384u + (unsigned)wave * 1024u +
                           (unsigned)s4 * 4096u;
            __builtin_amdgcn_global_load_lds(AS1(g + src), AS3(smem + dst), 16, 0, 0);
        }
    };

    stageTile(0);
    stageTile(2);
    {
        const char* gp = (const char*)(params + tiles[wave] * TILE);
        #pragma unroll
        for (int s2 = 0; s2 < 2; ++s2) {
            unsigned so  = (unsigned)s2 * 1024u + (unsigned)lane * 16u;
            unsigned dst = 65536u + (unsigned)wave * 2048u + (unsigned)s2 * 1024u;
            __builtin_amdgcn_global_load_lds(AS1(gp + so), AS3(smem + dst), 16, 0, 0);
        }
    }
    stageTile(1);
    stageTile(3);

    // A-side state, reloaded only when sa changes
    bf16x8 afrag[2][2];
    float rsq[2][4], rx[2][4], ry[2][4], rk[2][4];
    auto loadAside = [&](int sa) {
        const char* aB = smem + (unsigned)sa * 16384u;
        const float4* pA = (const float4*)(smem + 65536u + (unsigned)sa * 2048u);
        #pragma unroll
        for (int rb = 0; rb < 2; ++rb) {
            unsigned row = (unsigned)(wave * 32 + rb * 16 + fr);
            unsigned sw = (row & 7u) << 4;
            #pragma unroll
            for (int ks = 0; ks < 2; ++ks)
                afrag[rb][ks] = *(const bf16x8*)(
                    aB + row * 128u + (((unsigned)(ks * 64 + h * 16)) ^ sw));
            #pragma unroll
            for (int reg = 0; reg < 4; ++reg) {
                float4 rp = pA[wave * 32 + rb * 16 + h * 4 + reg];
                rsq[rb][reg] = rp.x; rx[rb][reg] = rp.y;
                ry[rb][reg] = rp.z;  rk[rb][reg] = rp.w;
            }
        }
    };

    auto computeItem = [&](int sb) -> float {
        const char* bB = smem + (unsigned)sb * 16384u;
        const float4* pB = (const float4*)(smem + 65536u + (unsigned)sb * 2048u);

        f32x4 acc[2][8];
        #pragma unroll
        for (int rb = 0; rb < 2; ++rb)
            #pragma unroll
            for (int cb = 0; cb < 8; ++cb)
                acc[rb][cb] = (f32x4){0.f, 0.f, 0.f, 0.f};

        #pragma unroll
        for (int cb = 0; cb < 8; ++cb) {
            unsigned rowB = (unsigned)(cb * 16 + fr);
            unsigned sw = (rowB & 7u) << 4;
            const char* bb = bB + rowB * 128u;
            bf16x8 b0 = *(const bf16x8*)(bb + (((unsigned)(h * 16)) ^ sw));
            bf16x8 b1 = *(const bf16x8*)(bb + (((unsigned)(64 + h * 16)) ^ sw));
            #pragma unroll
            for (int rb = 0; rb < 2; ++rb) {
                acc[rb][cb] = __builtin_amdgcn_mfma_f32_16x16x32_bf16(
                    afrag[rb][0], b0, acc[rb][cb], 0, 0, 0);
                acc[rb][cb] = __builtin_amdgcn_mfma_f32_16x16x32_bf16(
                    afrag[rb][1], b1, acc[rb][cb], 0, 0, 0);
            }
        }

        float tacc[2][4];
        #pragma unroll
        for (int rb = 0; rb < 2; ++rb)
            #pragma unroll
            for (int reg = 0; reg < 4; ++reg)
                tacc[rb][reg] = 0.f;

        #pragma unroll
        for (int cb = 0; cb < 8; ++cb) {
            float4 cp = pB[cb * 16 + fr];   // {csq, cx, cy, cK}
            #pragma unroll
            for (int rb = 0; rb < 2; ++rb)
                #pragma unroll
                for (int reg = 0; reg < 4; ++reg) {
                    float nd2 = rk[rb][reg] + cp.w;
                    nd2 = fmaf(ry[rb][reg], cp.z, nd2);
                    nd2 = fmaf(rx[rb][reg], cp.y, nd2);
                    float w = __builtin_amdgcn_exp2f(nd2);
                    float pd = fmaf(-2.f, acc[rb][cb][reg],
                                    rsq[rb][reg] + cp.x);
                    tacc[rb][reg] = fmaf(w, pd, tacc[rb][reg]);
                }
        }
        float tl = 0.f;
        #pragma unroll
        for (int rb = 0; rb < 2; ++rb)
            #pragma unroll
            for (int reg = 0; reg < 4; ++reg)
                tl += tacc[rb][reg];
        return tl;
    };

    float loss = 0.f;
    asm volatile("s_waitcnt vmcnt(8)" ::: "memory");  // slots 0,2 + params
    __syncthreads();
    loadAside(0);
    {
        float tl = computeItem(2);                    // (0,2)
        loss += diag ? tl : 2.f * tl;
    }
    asm volatile("s_waitcnt vmcnt(0)" ::: "memory");
    __syncthreads();
    loss += 2.f * computeItem(3);                     // (0,3)
    loadAside(1);
    if (!diag) loss += 2.f * computeItem(2);          // (1,2)
    {
        float tl = computeItem(3);                    // (1,3)
        loss += diag ? tl : 2.f * tl;
    }

    #pragma unroll
    for (int off = 32; off > 0; off >>= 1)
        loss += __shfl_down(loss, off, 64);
    if (lane == 0) red[wave] = loss;
    __syncthreads();
    if (tid == 0) {
        partial[blockIdx.x] = (red[0] + red[1]) + (red[2] + red[3]);
        __threadfence();
        unsigned old = atomicAdd(ctr, 1u);
        lastflag = (old == (unsigned)(NSUP - 1)) ? 1 : 0;
        if (lastflag) __threadfence();
    }
    __syncthreads();
    if (lastflag) {
        float s = 0.f;
        for (int idx = tid; idx < NSUP; idx += 256) s += partial[idx];
        #pragma unroll
        for (int off = 32; off > 0; off >>= 1)
            s += __shfl_down(s, off, 64);
        if (lane == 0) red[wave] = s;
        __syncthreads();
        if (tid == 0)
            out[0] = ((red[0] + red[1]) + (red[2] + red[3])) *
                     (1.0f / (8192.0f * 8192.0f));
    }
}

extern "C" void kernel_launch(void* const* d_in, const int* in_sizes, int n_in,
                              void* d_out, int out_size, void* d_ws, size_t ws_size,
                              hipStream_t stream) {
    const float* pred = (const float*)d_in[0];
    const float* spat = (const float*)d_in[1];
    float* out = (float*)d_out;

    ushort*   pbf     = (ushort*)d_ws;                                    // 1 MB
    float4*   params  = (float4*)((char*)d_ws + (size_t)NPTS * DIM * 2);  // 128 KB
    float*    partial = (float*)((char*)params + NPTS * sizeof(float4));  // 2.1 KB
    unsigned* ctr     = (unsigned*)(partial + ((NSUP + 3) & ~3));

    scl_prep_kernel<<<NPTS / 256, 256, 0, stream>>>(pred, spat, pbf, params, ctr);
    scl_mfma_kernel<<<NSUP, 256, 0, stream>>>(pbf, params, partial, ctr, out);
}